// Round 1
// baseline (1292.905 us; speedup 1.0000x reference)
//
#include <hip/hip_runtime.h>

#define DEV __device__ __forceinline__

typedef short bf16x8 __attribute__((ext_vector_type(8)));
typedef float f32x4 __attribute__((ext_vector_type(4)));

// ---------- helpers ----------
DEV short f2bf(float f) {
  union { float f; unsigned u; } un; un.f = f;
  unsigned r = un.u + 0x7FFFu + ((un.u >> 16) & 1u);  // RNE
  return (short)(r >> 16);
}
DEV float bf2f(short s) {
  union { unsigned u; float f; } un;
  un.u = ((unsigned)(unsigned short)s) << 16;
  return un.f;
}

DEV float blockReduceSum256(float v, volatile float* sbuf) {
  #pragma unroll
  for (int off = 32; off > 0; off >>= 1) v += __shfl_down(v, off, 64);
  const int wv = threadIdx.x >> 6, ln = threadIdx.x & 63;
  if (ln == 0) sbuf[wv] = v;
  __syncthreads();
  return sbuf[0] + sbuf[1] + sbuf[2] + sbuf[3];
}

// ---------- weight pack: transpose + bf16 cast ----------
// wT_val  : [384][768]  from w_val (768x384)
// wT_offaw: [432][768]  rows 0..287 from w_off (768x288), rows 288..431 from w_aw (768x144)
// wT_out  : [768][384]  from w_out (384x768)
// bias_cat: [432] = b_off ++ b_aw
__global__ __launch_bounds__(256) void pack_weights_kernel(
    const float* __restrict__ w_val, const float* __restrict__ w_off,
    const float* __restrict__ w_aw, const float* __restrict__ w_out,
    const float* __restrict__ b_off, const float* __restrict__ b_aw,
    short* __restrict__ wT_val, short* __restrict__ wT_offaw,
    short* __restrict__ wT_out, float* __restrict__ bias_cat) {
  int gid = blockIdx.x * 256 + threadIdx.x;
  const int S0 = 768 * 384, S1 = 768 * 288, S2 = 768 * 144, S3 = 384 * 768, S4 = 432;
  if (gid < S0) { int k = gid / 384, n = gid % 384; wT_val[n * 768 + k] = f2bf(w_val[gid]); return; }
  gid -= S0;
  if (gid < S1) { int k = gid / 288, n = gid % 288; wT_offaw[n * 768 + k] = f2bf(w_off[gid]); return; }
  gid -= S1;
  if (gid < S2) { int k = gid / 144, n = gid % 144; wT_offaw[(288 + n) * 768 + k] = f2bf(w_aw[gid]); return; }
  gid -= S2;
  if (gid < S3) { int k = gid / 768, n = gid % 768; wT_out[n * 384 + k] = f2bf(w_out[gid]); return; }
  gid -= S3;
  if (gid < S4) { bias_cat[gid] = (gid < 288) ? b_off[gid] : b_aw[gid - 288]; }
}

// ---------- LayerNorm row stats (mu, rsigma), 768 cols ----------
__global__ __launch_bounds__(256) void ln_stats_kernel(const float* __restrict__ x,
                                                       float2* __restrict__ st) {
  const int row = blockIdx.x;
  const float* xr = x + (size_t)row * 768;
  const int t = threadIdx.x;
  float a0 = xr[t], a1 = xr[t + 256], a2 = xr[t + 512];
  __shared__ float sb1[4], sb2[4];
  float mu = blockReduceSum256(a0 + a1 + a2, sb1) * (1.f / 768.f);
  float d0 = a0 - mu, d1 = a1 - mu, d2 = a2 - mu;
  float var = blockReduceSum256(d0 * d0 + d1 * d1 + d2 * d2, sb2) * (1.f / 768.f);
  if (t == 0) st[row] = make_float2(mu, rsqrtf(var + 1e-6f));
}

// ---------- generic 64x64-tile bf16 MFMA GEMM ----------
// AMODE 0: A = bf16 [M][K]
// AMODE 1: A = LN(Af f32 [M][768-ish K]) on the fly using st/lnw/lnb
// EMODE 0: store bf16 (acc + bias)
// EMODE 1: store f32  (acc + bias), N-guarded
// EMODE 2: store f32  qres + gamma*(acc + bias)   (residual epilogue)
template <int AMODE, int EMODE, bool NGUARD>
__global__ __launch_bounds__(256) void gemm64_kernel(
    const short* __restrict__ A, const float* __restrict__ Af,
    const float2* __restrict__ st, const float* __restrict__ lnw,
    const float* __restrict__ lnb, const short* __restrict__ Wt,
    const float* __restrict__ bias, const float* __restrict__ qres,
    const float* __restrict__ gamma, void* __restrict__ Cout,
    const int N, const int K) {
  __shared__ __align__(16) short As[64 * 40];
  __shared__ __align__(16) short Bs[64 * 40];
  const int tid = threadIdx.x;
  const int wave = tid >> 6, lane = tid & 63;
  const int sr = tid >> 2;          // staging row 0..63
  const int sk = (tid & 3) * 8;     // staging k offset 0/8/16/24
  const int n0 = blockIdx.x * 64;   // col tile
  const int row0 = blockIdx.y * 64; // row tile

  f32x4 acc[4];
  #pragma unroll
  for (int i = 0; i < 4; i++)
    #pragma unroll
    for (int j = 0; j < 4; j++) acc[i][j] = 0.f;

  const int lr = lane & 15, quad = lane >> 4;
  const short* AsF = &As[(wave * 16 + lr) * 40 + quad * 8];
  const short* BsF = &Bs[lr * 40 + quad * 8];

  float2 rowst = make_float2(0.f, 0.f);
  if (AMODE == 1) rowst = st[row0 + sr];

  for (int k0 = 0; k0 < K; k0 += 32) {
    // ---- stage A tile (64 x 32) ----
    if (AMODE == 0) {
      bf16x8 av = *(const bf16x8*)(A + (size_t)(row0 + sr) * K + k0 + sk);
      *(bf16x8*)(&As[sr * 40 + sk]) = av;
    } else {
      const float* p = Af + (size_t)(row0 + sr) * K + k0 + sk;
      float4 v0 = *(const float4*)p;
      float4 v1 = *(const float4*)(p + 4);
      const float* wp = lnw + k0 + sk;
      const float* bp = lnb + k0 + sk;
      float e[8] = {v0.x, v0.y, v0.z, v0.w, v1.x, v1.y, v1.z, v1.w};
      bf16x8 av;
      #pragma unroll
      for (int i = 0; i < 8; i++)
        av[i] = f2bf((e[i] - rowst.x) * rowst.y * wp[i] + bp[i]);
      *(bf16x8*)(&As[sr * 40 + sk]) = av;
    }
    // ---- stage B tile (64 cols x 32 k), Wt is [N][K] ----
    {
      bf16x8 bv;
      const int n = n0 + sr;
      if (!NGUARD || n < N) {
        bv = *(const bf16x8*)(Wt + (size_t)n * K + k0 + sk);
      } else {
        #pragma unroll
        for (int i = 0; i < 8; i++) bv[i] = 0;
      }
      *(bf16x8*)(&Bs[sr * 40 + sk]) = bv;
    }
    __syncthreads();
    // ---- MFMA ----
    bf16x8 af = *(const bf16x8*)AsF;
    #pragma unroll
    for (int cb = 0; cb < 4; cb++) {
      bf16x8 bf = *(const bf16x8*)(BsF + cb * 16 * 40);
      acc[cb] = __builtin_amdgcn_mfma_f32_16x16x32_bf16(af, bf, acc[cb], 0, 0, 0);
    }
    __syncthreads();
  }

  // ---- epilogue: C row = quad*4+i, col = lane&15 ----
  #pragma unroll
  for (int cb = 0; cb < 4; cb++) {
    const int n = n0 + cb * 16 + lr;
    if (NGUARD && n >= N) continue;
    const float bs = bias[n];
    #pragma unroll
    for (int i = 0; i < 4; i++) {
      const int m = row0 + wave * 16 + quad * 4 + i;
      float v = acc[cb][i] + bs;
      if (EMODE == 0) {
        ((short*)Cout)[(size_t)m * N + n] = f2bf(v);
      } else if (EMODE == 1) {
        ((float*)Cout)[(size_t)m * N + n] = v;
      } else {
        ((float*)Cout)[(size_t)m * N + n] =
            qres[(size_t)m * N + n] + gamma[n] * v;
      }
    }
  }
}

// ---------- sampler: softmax + bilinear gather + weighted sum ----------
// block = (b,q) pair, 384 threads: head = tid>>5 (12), ch = tid&31 (32)
__global__ __launch_bounds__(384) void sampler_kernel(
    const float* __restrict__ offaw,  // [16384][432]: 288 offsets + 144 aw logits
    const float* __restrict__ refp,   // [B][LQ][3][2]
    const short* __restrict__ value,  // bf16 [B*5376][384]
    short* __restrict__ o) {          // bf16 [16384][384]
  const int bq = blockIdx.x;
  const int tid = threadIdx.x;
  const int head = tid >> 5, ch = tid & 31;
  __shared__ float s[432];
  __shared__ float sref[6];
  const float* row = offaw + (size_t)bq * 432;
  for (int i = tid; i < 432; i += 384) s[i] = row[i];
  if (tid < 6) sref[tid] = refp[(size_t)bq * 6 + tid];
  __syncthreads();

  // softmax over the head's 12 logits (redundant across 32 lanes)
  const float* awp = &s[288 + head * 12];
  float mx = awp[0];
  #pragma unroll
  for (int j = 1; j < 12; j++) mx = fmaxf(mx, awp[j]);
  float wgt[12];
  float ssum = 0.f;
  #pragma unroll
  for (int j = 0; j < 12; j++) { float e = __expf(awp[j] - mx); wgt[j] = e; ssum += e; }
  const float inv = 1.f / ssum;

  const int b = bq >> 10;
  const short* vb = value + (size_t)b * 5376 * 384 + head * 32 + ch;
  float acc = 0.f;
  const int HW[3] = {64, 32, 16};
  const int starts[3] = {0, 4096, 5120};
  #pragma unroll
  for (int l = 0; l < 3; l++) {
    const int Wi = HW[l], Hi = HW[l];
    const float Wf = (float)Wi, Hf = (float)Hi;
    const float rx = sref[l * 2], ry = sref[l * 2 + 1];
    #pragma unroll
    for (int p = 0; p < 4; p++) {
      const int oi = ((head * 3 + l) * 4 + p) * 2;
      float x = (rx + s[oi] / Wf) * Wf - 0.5f;
      float y = (ry + s[oi + 1] / Hf) * Hf - 0.5f;
      float xf = floorf(x), yf = floorf(y);
      float dx = x - xf, dy = y - yf;
      int x0 = (int)xf, y0 = (int)yf;
      int x1 = x0 + 1, y1 = y0 + 1;
      bool vx0 = (x0 >= 0) & (x0 < Wi), vx1 = (x1 >= 0) & (x1 < Wi);
      bool vy0 = (y0 >= 0) & (y0 < Hi), vy1 = (y1 >= 0) & (y1 < Hi);
      float v00 = 0.f, v01 = 0.f, v10 = 0.f, v11 = 0.f;
      if (vx0 & vy0) v00 = bf2f(vb[(size_t)(starts[l] + y0 * Wi + x0) * 384]);
      if (vx1 & vy0) v01 = bf2f(vb[(size_t)(starts[l] + y0 * Wi + x1) * 384]);
      if (vx0 & vy1) v10 = bf2f(vb[(size_t)(starts[l] + y1 * Wi + x0) * 384]);
      if (vx1 & vy1) v11 = bf2f(vb[(size_t)(starts[l] + y1 * Wi + x1) * 384]);
      float sample = v00 * (1.f - dx) * (1.f - dy) + v01 * dx * (1.f - dy) +
                     v10 * (1.f - dx) * dy + v11 * dx * dy;
      acc += wgt[l * 4 + p] * sample;
    }
  }
  acc *= inv;
  o[(size_t)bq * 384 + head * 32 + ch] = f2bf(acc);
}

// ---------- launch ----------
extern "C" void kernel_launch(void* const* d_in, const int* in_sizes, int n_in,
                              void* d_out, int out_size, void* d_ws, size_t ws_size,
                              hipStream_t stream) {
  (void)in_sizes; (void)n_in; (void)out_size; (void)ws_size;
  const float* q     = (const float*)d_in[0];
  const float* refp  = (const float*)d_in[1];
  const float* kv    = (const float*)d_in[2];
  // d_in[3] spatial_shapes, d_in[4] level_start_index: compile-time constants
  const float* ln1w  = (const float*)d_in[5];
  const float* ln1b  = (const float*)d_in[6];
  const float* ln2w  = (const float*)d_in[7];
  const float* ln2b  = (const float*)d_in[8];
  const float* gamma = (const float*)d_in[9];
  const float* w_off = (const float*)d_in[10];
  const float* b_off = (const float*)d_in[11];
  const float* w_aw  = (const float*)d_in[12];
  const float* b_aw  = (const float*)d_in[13];
  const float* w_val = (const float*)d_in[14];
  const float* b_val = (const float*)d_in[15];
  const float* w_out = (const float*)d_in[16];
  const float* b_out = (const float*)d_in[17];
  float* out = (float*)d_out;

  char* wsp = (char*)d_ws;
  size_t cur = 0;
  auto alloc = [&](size_t bytes) -> void* {
    cur = (cur + 255) & ~(size_t)255;
    void* p = wsp + cur;
    cur += bytes;
    return p;
  };
  short*  wT_val   = (short*)alloc((size_t)384 * 768 * 2);
  short*  wT_offaw = (short*)alloc((size_t)432 * 768 * 2);
  short*  wT_out   = (short*)alloc((size_t)768 * 384 * 2);
  float*  bias_cat = (float*)alloc((size_t)432 * 4);
  float2* st_kv    = (float2*)alloc((size_t)86016 * 8);
  float2* st_q     = (float2*)alloc((size_t)16384 * 8);
  short*  value    = (short*)alloc((size_t)86016 * 384 * 2);
  float*  offaw    = (float*)alloc((size_t)16384 * 432 * 4);
  short*  obuf     = (short*)alloc((size_t)16384 * 384 * 2);

  pack_weights_kernel<<<3602, 256, 0, stream>>>(w_val, w_off, w_aw, w_out, b_off,
                                                b_aw, wT_val, wT_offaw, wT_out,
                                                bias_cat);
  ln_stats_kernel<<<86016, 256, 0, stream>>>(kv, st_kv);
  ln_stats_kernel<<<16384, 256, 0, stream>>>(q, st_q);
  // value = LN(kv) @ w_val + b_val   (M=86016, N=384, K=768) -> bf16
  gemm64_kernel<1, 0, false><<<dim3(6, 1344), 256, 0, stream>>>(
      nullptr, kv, st_kv, ln2w, ln2b, wT_val, b_val, nullptr, nullptr, value,
      384, 768);
  // offaw = LN(q) @ [w_off|w_aw] + bias_cat  (M=16384, N=432, K=768) -> f32
  gemm64_kernel<1, 1, true><<<dim3(7, 256), 256, 0, stream>>>(
      nullptr, q, st_q, ln1w, ln1b, wT_offaw, bias_cat, nullptr, nullptr, offaw,
      432, 768);
  // sampling + attention-weighted sum -> obuf bf16 (16384 x 384)
  sampler_kernel<<<16384, 384, 0, stream>>>(offaw, refp, value, obuf);
  // out = q + gamma * (obuf @ w_out + b_out)  (M=16384, N=768, K=384)
  gemm64_kernel<0, 2, false><<<dim3(12, 256), 256, 0, stream>>>(
      obuf, nullptr, nullptr, nullptr, nullptr, wT_out, b_out, q, gamma, out,
      768, 384);
}

// Round 2
// 742.584 us; speedup vs baseline: 1.7411x; 1.7411x over previous
//
#include <hip/hip_runtime.h>

#define DEV __device__ __forceinline__

typedef short bf16x8 __attribute__((ext_vector_type(8)));
typedef float f32x4 __attribute__((ext_vector_type(4)));

// ---------- helpers ----------
DEV short f2bf(float f) {
  union { float f; unsigned u; } un; un.f = f;
  unsigned r = un.u + 0x7FFFu + ((un.u >> 16) & 1u);  // RNE
  return (short)(r >> 16);
}
DEV float bf2f(unsigned short s) {
  union { unsigned u; float f; } un;
  un.u = ((unsigned)s) << 16;
  return un.f;
}

DEV float blockReduceSum256(float v, volatile float* sbuf) {
  #pragma unroll
  for (int off = 32; off > 0; off >>= 1) v += __shfl_down(v, off, 64);
  const int wv = threadIdx.x >> 6, ln = threadIdx.x & 63;
  if (ln == 0) sbuf[wv] = v;
  __syncthreads();
  return sbuf[0] + sbuf[1] + sbuf[2] + sbuf[3];
}

// ---------- weight pack: transpose + bf16 cast ----------
// wT_val  : [384][768]  from w_val (768x384)
// wT_offaw: [448][768]  rows 0..287 from w_off, 288..431 from w_aw, 432..447 zero pad
// wT_out  : [768][384]  from w_out (384x768)
// bias_cat: [448] = b_off ++ b_aw ++ 0-pad
__global__ __launch_bounds__(256) void pack_weights_kernel(
    const float* __restrict__ w_val, const float* __restrict__ w_off,
    const float* __restrict__ w_aw, const float* __restrict__ w_out,
    const float* __restrict__ b_off, const float* __restrict__ b_aw,
    short* __restrict__ wT_val, short* __restrict__ wT_offaw,
    short* __restrict__ wT_out, float* __restrict__ bias_cat) {
  int gid = blockIdx.x * 256 + threadIdx.x;
  const int S0 = 768 * 384, S1 = 768 * 288, S2 = 768 * 144, S3 = 384 * 768;
  const int S4 = 16 * 768, S5 = 448;
  if (gid < S0) { int k = gid / 384, n = gid % 384; wT_val[n * 768 + k] = f2bf(w_val[gid]); return; }
  gid -= S0;
  if (gid < S1) { int k = gid / 288, n = gid % 288; wT_offaw[n * 768 + k] = f2bf(w_off[gid]); return; }
  gid -= S1;
  if (gid < S2) { int k = gid / 144, n = gid % 144; wT_offaw[(288 + n) * 768 + k] = f2bf(w_aw[gid]); return; }
  gid -= S2;
  if (gid < S3) { int k = gid / 768, n = gid % 768; wT_out[n * 384 + k] = f2bf(w_out[gid]); return; }
  gid -= S3;
  if (gid < S4) { wT_offaw[432 * 768 + gid] = 0; return; }
  gid -= S4;
  if (gid < S5) { bias_cat[gid] = (gid < 288) ? b_off[gid] : (gid < 432 ? b_aw[gid - 288] : 0.f); }
}

// ---------- LayerNorm row stats (mu, rsigma), 768 cols ----------
__global__ __launch_bounds__(256) void ln_stats_kernel(const float* __restrict__ x,
                                                       float2* __restrict__ st) {
  const int row = blockIdx.x;
  const float* xr = x + (size_t)row * 768;
  const int t = threadIdx.x;
  float a0 = xr[t], a1 = xr[t + 256], a2 = xr[t + 512];
  __shared__ float sb1[4], sb2[4];
  float mu = blockReduceSum256(a0 + a1 + a2, sb1) * (1.f / 768.f);
  float d0 = a0 - mu, d1 = a1 - mu, d2 = a2 - mu;
  float var = blockReduceSum256(d0 * d0 + d1 * d1 + d2 * d2, sb2) * (1.f / 768.f);
  if (t == 0) st[row] = make_float2(mu, rsqrtf(var + 1e-6f));
}

// ---------- wide-N bf16 MFMA GEMM: 64 rows x (NT2*64) cols per block ----------
// Each of 4 waves owns 4 row-tiles x NT2 col-tiles (16x16x32 MFMA).
// A fetched exactly once per row-tile (grid.x covers N in BN=NT2*64 chunks).
// AMODE 0: A bf16 [M][K];  AMODE 1: A = LN(f32 Af) on the fly.
// EMODE 0: bf16 out (acc+bias); 1: f32 out (acc+bias); 2: f32 qres+gamma*(acc+bias)
template <int NT2, int AMODE, int EMODE>
__global__ __launch_bounds__(256, 2) void gemmw_kernel(
    const short* __restrict__ A, const float* __restrict__ Af,
    const float2* __restrict__ st, const float* __restrict__ lnw,
    const float* __restrict__ lnb, const short* __restrict__ Wt,
    const float* __restrict__ bias, const float* __restrict__ qres,
    const float* __restrict__ gamma, void* __restrict__ Cout,
    const int N, const int K) {
  constexpr int BN = NT2 * 64;
  __shared__ __align__(16) short As[64 * 40];
  __shared__ __align__(16) short Bs[BN * 40];
  const int tid = threadIdx.x;
  const int wave = tid >> 6, lane = tid & 63;
  const int sr = tid >> 2;         // staging row 0..63
  const int sk = (tid & 3) * 8;    // staging k offset
  const int n0 = blockIdx.x * BN;
  const int row0 = blockIdx.y * 64;
  const int lr = lane & 15, quad = lane >> 4;

  f32x4 acc[4][NT2];
  #pragma unroll
  for (int rt = 0; rt < 4; rt++)
    #pragma unroll
    for (int cb = 0; cb < NT2; cb++)
      #pragma unroll
      for (int j = 0; j < 4; j++) acc[rt][cb][j] = 0.f;

  const short* AsF = &As[lr * 40 + quad * 8];
  const short* BsF = &Bs[(wave * NT2 * 16 + lr) * 40 + quad * 8];

  float2 rowst = make_float2(0.f, 0.f);
  if (AMODE == 1) rowst = st[row0 + sr];

  for (int k0 = 0; k0 < K; k0 += 32) {
    // ---- stage A tile (64 x 32) ----
    if (AMODE == 0) {
      bf16x8 av = *(const bf16x8*)(A + (size_t)(row0 + sr) * K + k0 + sk);
      *(bf16x8*)(&As[sr * 40 + sk]) = av;
    } else {
      const float* p = Af + (size_t)(row0 + sr) * K + k0 + sk;
      float4 v0 = *(const float4*)p;
      float4 v1 = *(const float4*)(p + 4);
      const float* wp = lnw + k0 + sk;
      const float* bp = lnb + k0 + sk;
      float e[8] = {v0.x, v0.y, v0.z, v0.w, v1.x, v1.y, v1.z, v1.w};
      bf16x8 av;
      #pragma unroll
      for (int i = 0; i < 8; i++)
        av[i] = f2bf((e[i] - rowst.x) * rowst.y * wp[i] + bp[i]);
      *(bf16x8*)(&As[sr * 40 + sk]) = av;
    }
    // ---- stage B tile (BN x 32), Wt is [N][K] ----
    #pragma unroll
    for (int i = tid; i < BN * 4; i += 256) {
      int n = i >> 2, kk = (i & 3) * 8;
      *(bf16x8*)(&Bs[n * 40 + kk]) =
          *(const bf16x8*)(Wt + (size_t)(n0 + n) * K + k0 + kk);
    }
    __syncthreads();
    // ---- MFMA: 4 row-tiles x NT2 col-tiles ----
    bf16x8 af[4];
    #pragma unroll
    for (int rt = 0; rt < 4; rt++) af[rt] = *(const bf16x8*)(AsF + rt * 16 * 40);
    #pragma unroll
    for (int cb = 0; cb < NT2; cb++) {
      bf16x8 bf = *(const bf16x8*)(BsF + cb * 16 * 40);
      #pragma unroll
      for (int rt = 0; rt < 4; rt++)
        acc[rt][cb] = __builtin_amdgcn_mfma_f32_16x16x32_bf16(af[rt], bf, acc[rt][cb], 0, 0, 0);
    }
    __syncthreads();
  }

  // ---- epilogue: within a 16x16 tile, col = lane&15, row = quad*4+i ----
  #pragma unroll
  for (int cb = 0; cb < NT2; cb++) {
    const int n = n0 + wave * NT2 * 16 + cb * 16 + lr;
    const float bs = bias[n];
    const float gm = (EMODE == 2) ? gamma[n] : 0.f;
    #pragma unroll
    for (int rt = 0; rt < 4; rt++) {
      #pragma unroll
      for (int i = 0; i < 4; i++) {
        const int m = row0 + rt * 16 + quad * 4 + i;
        float v = acc[rt][cb][i] + bs;
        if (EMODE == 0) {
          ((short*)Cout)[(size_t)m * N + n] = f2bf(v);
        } else if (EMODE == 1) {
          ((float*)Cout)[(size_t)m * N + n] = v;
        } else {
          ((float*)Cout)[(size_t)m * N + n] =
              qres[(size_t)m * N + n] + gm * v;
        }
      }
    }
  }
}

// ---------- sampler: softmax + bilinear gather + weighted sum ----------
// 384 threads = 4 queries x (12 heads x 8 lanes); each lane owns 4 channels
// (ushort4 gathers). Clamped indices + zeroed weights (no divergent guards).
__global__ __launch_bounds__(384) void sampler_kernel(
    const float* __restrict__ offaw,  // [16384][448]: 288 off + 144 aw + pad
    const float* __restrict__ refp,   // [B][LQ][3][2]
    const short* __restrict__ value,  // bf16 [B*5376][384]
    short* __restrict__ o) {          // bf16 [16384][384]
  const int tid = threadIdx.x;
  const int qi = tid / 96, t = tid % 96;
  const int head = t >> 3, ln4 = t & 7;
  const int bq = blockIdx.x * 4 + qi;
  __shared__ __align__(16) float s[4][440];
  __shared__ float sref[4][6];
  const float* row = offaw + (size_t)bq * 448;
  #pragma unroll
  for (int i = t; i < 108; i += 96)
    *(float4*)&s[qi][i * 4] = *(const float4*)&row[i * 4];
  if (t < 6) sref[qi][t] = refp[(size_t)bq * 6 + t];
  __syncthreads();

  // softmax over this head's 12 logits (redundant across 8 lanes)
  const float* awp = &s[qi][288 + head * 12];
  float mx = awp[0];
  #pragma unroll
  for (int j = 1; j < 12; j++) mx = fmaxf(mx, awp[j]);
  float wgt[12];
  float ssum = 0.f;
  #pragma unroll
  for (int j = 0; j < 12; j++) { float e = __expf(awp[j] - mx); wgt[j] = e; ssum += e; }
  const float inv = 1.f / ssum;

  const int b = bq >> 10;
  const unsigned short* vb =
      (const unsigned short*)value + (size_t)b * 5376 * 384 + head * 32 + ln4 * 4;
  float4 acc = make_float4(0.f, 0.f, 0.f, 0.f);
  const int HW[3] = {64, 32, 16};
  const int starts[3] = {0, 4096, 5120};
  #pragma unroll
  for (int l = 0; l < 3; l++) {
    const int Wi = HW[l];
    const float Wf = (float)Wi;
    const float rx = sref[qi][l * 2], ry = sref[qi][l * 2 + 1];
    const unsigned short* base = vb + (size_t)starts[l] * 384;
    #pragma unroll
    for (int p = 0; p < 4; p++) {
      const int oi = ((head * 3 + l) * 4 + p) * 2;
      float x = fmaf(rx, Wf, s[qi][oi] - 0.5f);
      float y = fmaf(ry, Wf, s[qi][oi + 1] - 0.5f);
      float xf = floorf(x), yf = floorf(y);
      float dx = x - xf, dy = y - yf;
      int x0 = (int)xf, y0 = (int)yf;
      int x1 = x0 + 1, y1 = y0 + 1;
      int x0c = min(max(x0, 0), Wi - 1), x1c = min(max(x1, 0), Wi - 1);
      int y0c = min(max(y0, 0), Wi - 1), y1c = min(max(y1, 0), Wi - 1);
      float wx0 = (x0 >= 0 && x0 < Wi) ? (1.f - dx) : 0.f;
      float wx1 = (x1 < Wi && x1 >= 0) ? dx : 0.f;
      float wy0 = (y0 >= 0 && y0 < Wi) ? (1.f - dy) : 0.f;
      float wy1 = (y1 < Wi && y1 >= 0) ? dy : 0.f;
      const ushort4 u00 = *(const ushort4*)(base + (size_t)(y0c * Wi + x0c) * 384);
      const ushort4 u01 = *(const ushort4*)(base + (size_t)(y0c * Wi + x1c) * 384);
      const ushort4 u10 = *(const ushort4*)(base + (size_t)(y1c * Wi + x0c) * 384);
      const ushort4 u11 = *(const ushort4*)(base + (size_t)(y1c * Wi + x1c) * 384);
      const float w00 = wx0 * wy0, w01 = wx1 * wy0, w10 = wx0 * wy1, w11 = wx1 * wy1;
      const float g = wgt[l * 4 + p];
      acc.x += g * (w00 * bf2f(u00.x) + w01 * bf2f(u01.x) + w10 * bf2f(u10.x) + w11 * bf2f(u11.x));
      acc.y += g * (w00 * bf2f(u00.y) + w01 * bf2f(u01.y) + w10 * bf2f(u10.y) + w11 * bf2f(u11.y));
      acc.z += g * (w00 * bf2f(u00.z) + w01 * bf2f(u01.z) + w10 * bf2f(u10.z) + w11 * bf2f(u11.z));
      acc.w += g * (w00 * bf2f(u00.w) + w01 * bf2f(u01.w) + w10 * bf2f(u10.w) + w11 * bf2f(u11.w));
    }
  }
  ushort4 out;
  out.x = (unsigned short)f2bf(acc.x * inv);
  out.y = (unsigned short)f2bf(acc.y * inv);
  out.z = (unsigned short)f2bf(acc.z * inv);
  out.w = (unsigned short)f2bf(acc.w * inv);
  *(ushort4*)((unsigned short*)o + (size_t)bq * 384 + head * 32 + ln4 * 4) = out;
}

// ---------- launch ----------
extern "C" void kernel_launch(void* const* d_in, const int* in_sizes, int n_in,
                              void* d_out, int out_size, void* d_ws, size_t ws_size,
                              hipStream_t stream) {
  (void)in_sizes; (void)n_in; (void)out_size; (void)ws_size;
  const float* q     = (const float*)d_in[0];
  const float* refp  = (const float*)d_in[1];
  const float* kv    = (const float*)d_in[2];
  const float* ln1w  = (const float*)d_in[5];
  const float* ln1b  = (const float*)d_in[6];
  const float* ln2w  = (const float*)d_in[7];
  const float* ln2b  = (const float*)d_in[8];
  const float* gamma = (const float*)d_in[9];
  const float* w_off = (const float*)d_in[10];
  const float* b_off = (const float*)d_in[11];
  const float* w_aw  = (const float*)d_in[12];
  const float* b_aw  = (const float*)d_in[13];
  const float* w_val = (const float*)d_in[14];
  const float* b_val = (const float*)d_in[15];
  const float* w_out = (const float*)d_in[16];
  const float* b_out = (const float*)d_in[17];
  float* out = (float*)d_out;

  char* wsp = (char*)d_ws;
  size_t cur = 0;
  auto alloc = [&](size_t bytes) -> void* {
    cur = (cur + 255) & ~(size_t)255;
    void* p = wsp + cur;
    cur += bytes;
    return p;
  };
  short*  wT_val   = (short*)alloc((size_t)384 * 768 * 2);
  short*  wT_offaw = (short*)alloc((size_t)448 * 768 * 2);
  short*  wT_out   = (short*)alloc((size_t)768 * 384 * 2);
  float*  bias_cat = (float*)alloc((size_t)448 * 4);
  float2* st_kv    = (float2*)alloc((size_t)86016 * 8);
  float2* st_q     = (float2*)alloc((size_t)16384 * 8);
  short*  value    = (short*)alloc((size_t)86016 * 384 * 2);
  float*  offaw    = (float*)alloc((size_t)16384 * 448 * 4);
  short*  obuf     = (short*)alloc((size_t)16384 * 384 * 2);

  pack_weights_kernel<<<3651, 256, 0, stream>>>(w_val, w_off, w_aw, w_out, b_off,
                                                b_aw, wT_val, wT_offaw, wT_out,
                                                bias_cat);
  ln_stats_kernel<<<86016, 256, 0, stream>>>(kv, st_kv);
  ln_stats_kernel<<<16384, 256, 0, stream>>>(q, st_q);
  // value = LN(kv) @ w_val + b_val   (M=86016, N=384, K=768) -> bf16
  gemmw_kernel<6, 1, 0><<<dim3(1, 1344), 256, 0, stream>>>(
      nullptr, kv, st_kv, ln2w, ln2b, wT_val, b_val, nullptr, nullptr, value,
      384, 768);
  // offaw = LN(q) @ [w_off|w_aw|pad] + bias  (M=16384, N=448, K=768) -> f32
  gemmw_kernel<7, 1, 1><<<dim3(1, 256), 256, 0, stream>>>(
      nullptr, q, st_q, ln1w, ln1b, wT_offaw, bias_cat, nullptr, nullptr, offaw,
      448, 768);
  // sampling + attention-weighted sum -> obuf bf16 (16384 x 384)
  sampler_kernel<<<4096, 384, 0, stream>>>(offaw, refp, value, obuf);
  // out = q + gamma * (obuf @ w_out + b_out)  (M=16384, N=768, K=384)
  gemmw_kernel<6, 0, 2><<<dim3(2, 256), 256, 0, stream>>>(
      obuf, nullptr, nullptr, nullptr, nullptr, wT_out, b_out, q, gamma, out,
      768, 384);
}

// Round 3
// 732.404 us; speedup vs baseline: 1.7653x; 1.0139x over previous
//
#include <hip/hip_runtime.h>

#define DEV __device__ __forceinline__

typedef short bf16x8 __attribute__((ext_vector_type(8)));
typedef float f32x4 __attribute__((ext_vector_type(4)));
typedef unsigned int u32;
typedef __attribute__((address_space(1))) const u32* gas_ptr;
typedef __attribute__((address_space(3))) u32* las_ptr;

// ---------- helpers ----------
DEV short f2bf(float f) {
  union { float f; unsigned u; } un; un.f = f;
  unsigned r = un.u + 0x7FFFu + ((un.u >> 16) & 1u);  // RNE
  return (short)(r >> 16);
}
DEV float bf2f(unsigned short s) {
  union { unsigned u; float f; } un;
  un.u = ((unsigned)s) << 16;
  return un.f;
}
DEV void gload16(const short* g, short* l) {
  // async global->LDS, 16B per lane; LDS dest = wave-uniform base + lane*16
  __builtin_amdgcn_global_load_lds((gas_ptr)g, (las_ptr)l, 16, 0, 0);
}

DEV float blockReduceSum256(float v, volatile float* sbuf) {
  #pragma unroll
  for (int off = 32; off > 0; off >>= 1) v += __shfl_down(v, off, 64);
  const int wv = threadIdx.x >> 6, ln = threadIdx.x & 63;
  if (ln == 0) sbuf[wv] = v;
  __syncthreads();
  return sbuf[0] + sbuf[1] + sbuf[2] + sbuf[3];
}

// ---------- weight pack: transpose + bf16 cast ----------
__global__ __launch_bounds__(256) void pack_weights_kernel(
    const float* __restrict__ w_val, const float* __restrict__ w_off,
    const float* __restrict__ w_aw, const float* __restrict__ w_out,
    const float* __restrict__ b_off, const float* __restrict__ b_aw,
    short* __restrict__ wT_val, short* __restrict__ wT_offaw,
    short* __restrict__ wT_out, float* __restrict__ bias_cat) {
  int gid = blockIdx.x * 256 + threadIdx.x;
  const int S0 = 768 * 384, S1 = 768 * 288, S2 = 768 * 144, S3 = 384 * 768;
  const int S4 = 16 * 768, S5 = 448;
  if (gid < S0) { int k = gid / 384, n = gid % 384; wT_val[n * 768 + k] = f2bf(w_val[gid]); return; }
  gid -= S0;
  if (gid < S1) { int k = gid / 288, n = gid % 288; wT_offaw[n * 768 + k] = f2bf(w_off[gid]); return; }
  gid -= S1;
  if (gid < S2) { int k = gid / 144, n = gid % 144; wT_offaw[(288 + n) * 768 + k] = f2bf(w_aw[gid]); return; }
  gid -= S2;
  if (gid < S3) { int k = gid / 768, n = gid % 768; wT_out[n * 384 + k] = f2bf(w_out[gid]); return; }
  gid -= S3;
  if (gid < S4) { wT_offaw[432 * 768 + gid] = 0; return; }
  gid -= S4;
  if (gid < S5) { bias_cat[gid] = (gid < 288) ? b_off[gid] : (gid < 432 ? b_aw[gid - 288] : 0.f); }
}

// ---------- fused LayerNorm -> bf16 (768 cols, 1 row per block) ----------
__global__ __launch_bounds__(256) void ln_norm_kernel(
    const float* __restrict__ x, const float* __restrict__ w,
    const float* __restrict__ b, short* __restrict__ y) {
  const int row = blockIdx.x;
  const float* xr = x + (size_t)row * 768;
  const int t = threadIdx.x;
  float a0 = xr[t], a1 = xr[t + 256], a2 = xr[t + 512];
  __shared__ float sb1[4], sb2[4];
  float mu = blockReduceSum256(a0 + a1 + a2, sb1) * (1.f / 768.f);
  float d0 = a0 - mu, d1 = a1 - mu, d2 = a2 - mu;
  float var = blockReduceSum256(d0 * d0 + d1 * d1 + d2 * d2, sb2) * (1.f / 768.f);
  const float rs = rsqrtf(var + 1e-6f);
  short* yr = y + (size_t)row * 768;
  yr[t]       = f2bf(d0 * rs * w[t]       + b[t]);
  yr[t + 256] = f2bf(d1 * rs * w[t + 256] + b[t + 256]);
  yr[t + 512] = f2bf(d2 * rs * w[t + 512] + b[t + 512]);
}

// ---------- 128x128 bf16 MFMA GEMM, async global->LDS staging ----------
// XOR-swizzled LDS: tile [128 rows][32 k] stored as 64 lines x 8 granules(16B);
// A[r][q*8..] lives at (line=r>>1, pos=((r&1)*4+q)^(line&7)). Staging writes
// linear granules (global_load_lds constraint); ds_read_b128 fragments hit 8
// distinct bank-quads x2 => conflict-free. 4 waves 2x2, each 4x4 16x16x32 MFMA.
// EMODE 0: bf16 out (acc+bias); EMODE 2: f32 qres + gamma*(acc+bias)
template <int EMODE>
__global__ __launch_bounds__(256, 3) void gemm128_kernel(
    const short* __restrict__ A, const short* __restrict__ Wt,
    const float* __restrict__ bias, const float* __restrict__ qres,
    const float* __restrict__ gamma, void* __restrict__ Cout,
    const int N, const int K) {
  __shared__ __align__(16) short As[128 * 32];
  __shared__ __align__(16) short Bs[128 * 32];
  const int tid = threadIdx.x;
  const int wave = tid >> 6, lane = tid & 63;
  const int n0 = blockIdx.x * 128, row0 = blockIdx.y * 128;
  const int lr = lane & 15, quad = lane >> 4;
  const int wm = wave >> 1, wn = wave & 1;

  // staging source coords: round rnd granule G = rnd*256 + wave*64 + lane
  const short* gA[2]; const short* gB[2];
  #pragma unroll
  for (int rnd = 0; rnd < 2; rnd++) {
    int G = rnd * 256 + wave * 64 + lane;
    int line = G >> 3, pos = G & 7, x = pos ^ (line & 7);
    int r = line * 2 + (x >> 2), qk = (x & 3) * 8;
    gA[rnd] = A + (size_t)(row0 + r) * K + qk;
    gB[rnd] = Wt + (size_t)(n0 + r) * K + qk;
  }
  short* ldsA[2] = {&As[(wave * 64) * 8], &As[(256 + wave * 64) * 8]};
  short* ldsB[2] = {&Bs[(wave * 64) * 8], &Bs[(256 + wave * 64) * 8]};

  // fragment read addresses (fixed)
  const short* aF[4]; const short* bF[4];
  #pragma unroll
  for (int t4 = 0; t4 < 4; t4++) {
    int r = wm * 64 + t4 * 16 + lr;
    int line = r >> 1, pos = ((r & 1) * 4 + quad) ^ (line & 7);
    aF[t4] = &As[(line * 8 + pos) * 8];
    int rb = wn * 64 + t4 * 16 + lr;
    int lineb = rb >> 1, posb = ((rb & 1) * 4 + quad) ^ (lineb & 7);
    bF[t4] = &Bs[(lineb * 8 + posb) * 8];
  }

  f32x4 acc[4][4];
  #pragma unroll
  for (int i = 0; i < 4; i++)
    #pragma unroll
    for (int j = 0; j < 4; j++)
      #pragma unroll
      for (int e = 0; e < 4; e++) acc[i][j][e] = 0.f;

  for (int k0 = 0; k0 < K; k0 += 32) {
    gload16(gA[0], ldsA[0]);
    gload16(gA[1], ldsA[1]);
    gload16(gB[0], ldsB[0]);
    gload16(gB[1], ldsB[1]);
    gA[0] += 32; gA[1] += 32; gB[0] += 32; gB[1] += 32;
    __syncthreads();
    bf16x8 av[4], bv[4];
    #pragma unroll
    for (int t4 = 0; t4 < 4; t4++) {
      av[t4] = *(const bf16x8*)aF[t4];
      bv[t4] = *(const bf16x8*)bF[t4];
    }
    #pragma unroll
    for (int ct = 0; ct < 4; ct++)
      #pragma unroll
      for (int rt = 0; rt < 4; rt++)
        acc[rt][ct] = __builtin_amdgcn_mfma_f32_16x16x32_bf16(av[rt], bv[ct], acc[rt][ct], 0, 0, 0);
    __syncthreads();
  }

  // epilogue: tile col = lane&15, row = quad*4+i
  #pragma unroll
  for (int ct = 0; ct < 4; ct++) {
    const int n = n0 + wn * 64 + ct * 16 + lr;
    const float bs = bias[n];
    const float gm = (EMODE == 2) ? gamma[n] : 0.f;
    #pragma unroll
    for (int rt = 0; rt < 4; rt++) {
      #pragma unroll
      for (int i = 0; i < 4; i++) {
        const int m = row0 + wm * 64 + rt * 16 + quad * 4 + i;
        float v = acc[rt][ct][i] + bs;
        if (EMODE == 0) {
          ((short*)Cout)[(size_t)m * N + n] = f2bf(v);
        } else {
          ((float*)Cout)[(size_t)m * N + n] = qres[(size_t)m * N + n] + gm * v;
        }
      }
    }
  }
}

// ---------- wide-N bf16 GEMM (for N=448 offaw): 64 rows x NT2*64 cols ----------
template <int NT2>
__global__ __launch_bounds__(256, 2) void gemmw_kernel(
    const short* __restrict__ A, const short* __restrict__ Wt,
    const float* __restrict__ bias, float* __restrict__ Cout,
    const int N, const int K) {
  constexpr int BN = NT2 * 64;
  __shared__ __align__(16) short As[64 * 40];
  __shared__ __align__(16) short Bs[BN * 40];
  const int tid = threadIdx.x;
  const int wave = tid >> 6, lane = tid & 63;
  const int sr = tid >> 2;
  const int sk = (tid & 3) * 8;
  const int n0 = blockIdx.x * BN;
  const int row0 = blockIdx.y * 64;
  const int lr = lane & 15, quad = lane >> 4;

  f32x4 acc[4][NT2];
  #pragma unroll
  for (int rt = 0; rt < 4; rt++)
    #pragma unroll
    for (int cb = 0; cb < NT2; cb++)
      #pragma unroll
      for (int j = 0; j < 4; j++) acc[rt][cb][j] = 0.f;

  const short* AsF = &As[lr * 40 + quad * 8];
  const short* BsF = &Bs[(wave * NT2 * 16 + lr) * 40 + quad * 8];

  for (int k0 = 0; k0 < K; k0 += 32) {
    bf16x8 av = *(const bf16x8*)(A + (size_t)(row0 + sr) * K + k0 + sk);
    *(bf16x8*)(&As[sr * 40 + sk]) = av;
    #pragma unroll
    for (int i = tid; i < BN * 4; i += 256) {
      int n = i >> 2, kk = (i & 3) * 8;
      *(bf16x8*)(&Bs[n * 40 + kk]) =
          *(const bf16x8*)(Wt + (size_t)(n0 + n) * K + k0 + kk);
    }
    __syncthreads();
    bf16x8 af[4];
    #pragma unroll
    for (int rt = 0; rt < 4; rt++) af[rt] = *(const bf16x8*)(AsF + rt * 16 * 40);
    #pragma unroll
    for (int cb = 0; cb < NT2; cb++) {
      bf16x8 bfv = *(const bf16x8*)(BsF + cb * 16 * 40);
      #pragma unroll
      for (int rt = 0; rt < 4; rt++)
        acc[rt][cb] = __builtin_amdgcn_mfma_f32_16x16x32_bf16(af[rt], bfv, acc[rt][cb], 0, 0, 0);
    }
    __syncthreads();
  }

  #pragma unroll
  for (int cb = 0; cb < NT2; cb++) {
    const int n = n0 + wave * NT2 * 16 + cb * 16 + lr;
    const float bs = bias[n];
    #pragma unroll
    for (int rt = 0; rt < 4; rt++) {
      #pragma unroll
      for (int i = 0; i < 4; i++) {
        const int m = row0 + rt * 16 + quad * 4 + i;
        Cout[(size_t)m * N + n] = acc[rt][cb][i] + bs;
      }
    }
  }
}

// ---------- sampler: softmax + bilinear gather + weighted sum ----------
__global__ __launch_bounds__(384) void sampler_kernel(
    const float* __restrict__ offaw,  // [16384][448]
    const float* __restrict__ refp,   // [B][LQ][3][2]
    const short* __restrict__ value,  // bf16 [B*5376][384]
    short* __restrict__ o) {          // bf16 [16384][384]
  const int tid = threadIdx.x;
  const int qi = tid / 96, t = tid % 96;
  const int head = t >> 3, ln4 = t & 7;
  const int bq = blockIdx.x * 4 + qi;
  __shared__ __align__(16) float s[4][440];
  __shared__ float sref[4][6];
  const float* row = offaw + (size_t)bq * 448;
  #pragma unroll
  for (int i = t; i < 108; i += 96)
    *(float4*)&s[qi][i * 4] = *(const float4*)&row[i * 4];
  if (t < 6) sref[qi][t] = refp[(size_t)bq * 6 + t];
  __syncthreads();

  const float* awp = &s[qi][288 + head * 12];
  float mx = awp[0];
  #pragma unroll
  for (int j = 1; j < 12; j++) mx = fmaxf(mx, awp[j]);
  float wgt[12];
  float ssum = 0.f;
  #pragma unroll
  for (int j = 0; j < 12; j++) { float e = __expf(awp[j] - mx); wgt[j] = e; ssum += e; }
  const float inv = 1.f / ssum;

  const int b = bq >> 10;
  const unsigned short* vb =
      (const unsigned short*)value + (size_t)b * 5376 * 384 + head * 32 + ln4 * 4;
  float4 acc = make_float4(0.f, 0.f, 0.f, 0.f);
  const int HW[3] = {64, 32, 16};
  const int starts[3] = {0, 4096, 5120};
  #pragma unroll
  for (int l = 0; l < 3; l++) {
    const int Wi = HW[l];
    const float Wf = (float)Wi;
    const float rx = sref[qi][l * 2], ry = sref[qi][l * 2 + 1];
    const unsigned short* base = vb + (size_t)starts[l] * 384;
    #pragma unroll
    for (int p = 0; p < 4; p++) {
      const int oi = ((head * 3 + l) * 4 + p) * 2;
      float x = fmaf(rx, Wf, s[qi][oi] - 0.5f);
      float y = fmaf(ry, Wf, s[qi][oi + 1] - 0.5f);
      float xf = floorf(x), yf = floorf(y);
      float dx = x - xf, dy = y - yf;
      int x0 = (int)xf, y0 = (int)yf;
      int x1 = x0 + 1, y1 = y0 + 1;
      int x0c = min(max(x0, 0), Wi - 1), x1c = min(max(x1, 0), Wi - 1);
      int y0c = min(max(y0, 0), Wi - 1), y1c = min(max(y1, 0), Wi - 1);
      float wx0 = (x0 >= 0 && x0 < Wi) ? (1.f - dx) : 0.f;
      float wx1 = (x1 < Wi && x1 >= 0) ? dx : 0.f;
      float wy0 = (y0 >= 0 && y0 < Wi) ? (1.f - dy) : 0.f;
      float wy1 = (y1 < Wi && y1 >= 0) ? dy : 0.f;
      const ushort4 u00 = *(const ushort4*)(base + (size_t)(y0c * Wi + x0c) * 384);
      const ushort4 u01 = *(const ushort4*)(base + (size_t)(y0c * Wi + x1c) * 384);
      const ushort4 u10 = *(const ushort4*)(base + (size_t)(y1c * Wi + x0c) * 384);
      const ushort4 u11 = *(const ushort4*)(base + (size_t)(y1c * Wi + x1c) * 384);
      const float w00 = wx0 * wy0, w01 = wx1 * wy0, w10 = wx0 * wy1, w11 = wx1 * wy1;
      const float g = wgt[l * 4 + p];
      acc.x += g * (w00 * bf2f(u00.x) + w01 * bf2f(u01.x) + w10 * bf2f(u10.x) + w11 * bf2f(u11.x));
      acc.y += g * (w00 * bf2f(u00.y) + w01 * bf2f(u01.y) + w10 * bf2f(u10.y) + w11 * bf2f(u11.y));
      acc.z += g * (w00 * bf2f(u00.z) + w01 * bf2f(u01.z) + w10 * bf2f(u10.z) + w11 * bf2f(u11.z));
      acc.w += g * (w00 * bf2f(u00.w) + w01 * bf2f(u01.w) + w10 * bf2f(u10.w) + w11 * bf2f(u11.w));
    }
  }
  ushort4 outv;
  outv.x = (unsigned short)f2bf(acc.x * inv);
  outv.y = (unsigned short)f2bf(acc.y * inv);
  outv.z = (unsigned short)f2bf(acc.z * inv);
  outv.w = (unsigned short)f2bf(acc.w * inv);
  *(ushort4*)((unsigned short*)o + (size_t)bq * 384 + head * 32 + ln4 * 4) = outv;
}

// ---------- launch ----------
extern "C" void kernel_launch(void* const* d_in, const int* in_sizes, int n_in,
                              void* d_out, int out_size, void* d_ws, size_t ws_size,
                              hipStream_t stream) {
  (void)in_sizes; (void)n_in; (void)out_size; (void)ws_size;
  const float* q     = (const float*)d_in[0];
  const float* refp  = (const float*)d_in[1];
  const float* kv    = (const float*)d_in[2];
  const float* ln1w  = (const float*)d_in[5];
  const float* ln1b  = (const float*)d_in[6];
  const float* ln2w  = (const float*)d_in[7];
  const float* ln2b  = (const float*)d_in[8];
  const float* gamma = (const float*)d_in[9];
  const float* w_off = (const float*)d_in[10];
  const float* b_off = (const float*)d_in[11];
  const float* w_aw  = (const float*)d_in[12];
  const float* b_aw  = (const float*)d_in[13];
  const float* w_val = (const float*)d_in[14];
  const float* b_val = (const float*)d_in[15];
  const float* w_out = (const float*)d_in[16];
  const float* b_out = (const float*)d_in[17];
  float* out = (float*)d_out;

  char* wsp = (char*)d_ws;
  size_t cur = 0;
  auto alloc = [&](size_t bytes) -> void* {
    cur = (cur + 255) & ~(size_t)255;
    void* p = wsp + cur;
    cur += bytes;
    return p;
  };
  short*  wT_val   = (short*)alloc((size_t)384 * 768 * 2);
  short*  wT_offaw = (short*)alloc((size_t)448 * 768 * 2);
  short*  wT_out   = (short*)alloc((size_t)768 * 384 * 2);
  float*  bias_cat = (float*)alloc((size_t)448 * 4);
  short*  kvn      = (short*)alloc((size_t)86016 * 768 * 2);
  short*  qn       = (short*)alloc((size_t)16384 * 768 * 2);
  short*  value    = (short*)alloc((size_t)86016 * 384 * 2);
  float*  offaw    = (float*)alloc((size_t)16384 * 448 * 4);
  short*  obuf     = (short*)alloc((size_t)16384 * 384 * 2);

  pack_weights_kernel<<<3651, 256, 0, stream>>>(w_val, w_off, w_aw, w_out, b_off,
                                                b_aw, wT_val, wT_offaw, wT_out,
                                                bias_cat);
  ln_norm_kernel<<<86016, 256, 0, stream>>>(kv, ln2w, ln2b, kvn);
  ln_norm_kernel<<<16384, 256, 0, stream>>>(q, ln1w, ln1b, qn);
  // value = kvn @ w_val + b_val   (M=86016, N=384, K=768) -> bf16
  gemm128_kernel<0><<<dim3(3, 672), 256, 0, stream>>>(
      kvn, wT_val, b_val, nullptr, nullptr, value, 384, 768);
  // offaw = qn @ [w_off|w_aw|pad] + bias  (M=16384, N=448, K=768) -> f32
  gemmw_kernel<7><<<dim3(1, 256), 256, 0, stream>>>(
      qn, wT_offaw, bias_cat, offaw, 448, 768);
  // sampling + attention-weighted sum -> obuf bf16 (16384 x 384)
  sampler_kernel<<<4096, 384, 0, stream>>>(offaw, refp, value, obuf);
  // out = q + gamma * (obuf @ w_out + b_out)  (M=16384, N=768, K=384)
  gemm128_kernel<2><<<dim3(6, 128), 256, 0, stream>>>(
      obuf, wT_out, b_out, q, gamma, out, 768, 384);
}